// Round 4
// baseline (323.360 us; speedup 1.0000x reference)
//
#include <hip/hip_runtime.h>
#include <math.h>

// s = sum_i R[i] * ||Z[i,:]||^2 ;  out = 1 - exp(-exp(s))
// Z: (500000,128) fp32 = 256 MB (streamed once), R: 2 MB (L2-resident).
// Memory-bound: 258 MB read -> ~41 us floor at 6.3 TB/s achievable.
// Little's law: need ~5-9 KB in-flight per CU to hit HBM BW; this version
// keeps 25 16B loads in flight per thread (~4.8 KB/CU at 3 waves/SIMD).

#define NROWS   500000
#define DCOLS   128
#define N4      (NROWS * DCOLS / 4)   // 16,000,000 float4
#define BLOCK   256
#define GRID    2500
#define NTHREADS (GRID * BLOCK)       // 640,000 -> exactly 25 float4/thread
#define ITER    25

// native clang vector (not HIP_vector_type struct) so nontemporal builtin accepts it
typedef float floatx4 __attribute__((ext_vector_type(4)));

__global__ void __launch_bounds__(BLOCK)
bp_reduce(const float* __restrict__ Z, const float* __restrict__ R,
          float* __restrict__ partial) {
    const floatx4* __restrict__ Z4 = (const floatx4*)Z;
    const int tid = blockIdx.x * BLOCK + threadIdx.x;

    // Issue ALL loads up-front: 25 independent dwordx4 in flight per thread.
    floatx4 v[ITER];
    float   w[ITER];
    #pragma unroll
    for (int u = 0; u < ITER; ++u) {
        const int idx = tid + u * NTHREADS;
        v[u] = __builtin_nontemporal_load(&Z4[idx]);  // Z streamed once: bypass cache fill
        w[u] = R[idx >> 5];   // float4 idx -> row = (4*idx)/128; 32 lanes share -> L1 broadcast
    }

    float acc = 0.0f;
    #pragma unroll
    for (int u = 0; u < ITER; ++u)
        acc += w[u] * (v[u].x * v[u].x + v[u].y * v[u].y +
                       v[u].z * v[u].z + v[u].w * v[u].w);

    // wave(64) shuffle reduction
    #pragma unroll
    for (int off = 32; off > 0; off >>= 1)
        acc += __shfl_down(acc, off, 64);

    __shared__ float smem[BLOCK / 64];
    const int wave = threadIdx.x >> 6;
    const int lane = threadIdx.x & 63;
    if (lane == 0) smem[wave] = acc;
    __syncthreads();

    if (threadIdx.x == 0)
        partial[blockIdx.x] = smem[0] + smem[1] + smem[2] + smem[3];
        // unconditional write per block: no zero-init of d_ws needed
}

__global__ void __launch_bounds__(BLOCK)
bp_finalize(const float* __restrict__ partial, float* __restrict__ out) {
    float acc = 0.0f;
    for (int i = threadIdx.x; i < GRID; i += BLOCK)
        acc += partial[i];

    #pragma unroll
    for (int off = 32; off > 0; off >>= 1)
        acc += __shfl_down(acc, off, 64);

    __shared__ float smem[BLOCK / 64];
    const int wave = threadIdx.x >> 6;
    const int lane = threadIdx.x & 63;
    if (lane == 0) smem[wave] = acc;
    __syncthreads();

    if (threadIdx.x == 0) {
        float s = smem[0] + smem[1] + smem[2] + smem[3];
        float lam = expf(s);
        out[0] = 1.0f - expf(-lam);
    }
}

extern "C" void kernel_launch(void* const* d_in, const int* in_sizes, int n_in,
                              void* d_out, int out_size, void* d_ws, size_t ws_size,
                              hipStream_t stream) {
    const float* Z = (const float*)d_in[0];
    const float* R = (const float*)d_in[1];
    float* out = (float*)d_out;
    float* partial = (float*)d_ws;   // 2500 floats = 10 KB << ws_size

    bp_reduce<<<GRID, BLOCK, 0, stream>>>(Z, R, partial);
    bp_finalize<<<1, BLOCK, 0, stream>>>(partial, out);
}